// Round 1
// baseline (1889.031 us; speedup 1.0000x reference)
//
#include <hip/hip_runtime.h>

#define NN 100000
#define EE 600000
#define HH 128
#define GG 4000
#define TT 128

// ---------------- degree / dinv ----------------
__global__ __launch_bounds__(256) void deg_count_k(const int* __restrict__ ei,
                                                   float* __restrict__ deg) {
  int e = blockIdx.x * 256 + threadIdx.x;
  if (e < EE) atomicAdd(&deg[ei[EE + e]], 1.0f);   // dst row of edge_index
}

__global__ __launch_bounds__(256) void dinv_k(float* __restrict__ deg) {
  int n = blockIdx.x * 256 + threadIdx.x;
  if (n < NN) deg[n] = rsqrtf(deg[n] + 1.0f);      // +1 self-loop
}

// ---------------- atom encoder ----------------
// h0[n][h] = sum_f emb[x[n][f] + off[f]][h].  2 nodes per 256-thread block.
__global__ __launch_bounds__(256) void atom_enc_k(const int* __restrict__ x,
                                                  const float* __restrict__ emb,
                                                  float* __restrict__ h0) {
  __shared__ int xs[2][9];
  const int local = threadIdx.x >> 7;   // 0..1
  const int lane  = threadIdx.x & 127;  // 0..127
  const int n = blockIdx.x * 2 + local; // grid = NN/2 exactly (NN even)
  if (lane < 9) xs[local][lane] = x[n * 9 + lane];
  __syncthreads();
  const int off[9] = {0, 119, 124, 136, 148, 158, 164, 170, 172};
  float s = 0.0f;
#pragma unroll
  for (int f = 0; f < 9; f++)
    s += emb[(size_t)(xs[local][f] + off[f]) * HH + lane];
  h0[(size_t)n * HH + lane] = s;
}

// ---------------- fused GEMM + self-loop/bias epilogue ----------------
// Tm  = (RELU? relu(A) : A) @ W            [N,H]
// Agg = dinv^2 * Tm + b                     [N,H]   (may alias A: block only
//                                                    writes rows it alone read)
// BM=64, BN=128(full), BK=16; 256 threads; each thread 8x4 outputs.
template <bool RELU>
__global__ __launch_bounds__(256) void gemm_fused_k(const float* __restrict__ A,
                                                    const float* __restrict__ W,
                                                    const float* __restrict__ b,
                                                    const float* __restrict__ dinv,
                                                    float* __restrict__ Tm,
                                                    float* __restrict__ Agg) {
  __shared__ float As[16][64];    // [k][m]
  __shared__ float Ws[16][128];   // [k][n]
  const int t = threadIdx.x;
  const int block_m = blockIdx.x * 64;
  const int tm = t >> 5;                 // 0..7 -> rows tm*8..tm*8+7
  const int tn = t & 31;                 // 0..31 -> cols tn*4..tn*4+3
  const int arow = t >> 2;               // 0..63
  const int akq  = (t & 3) * 4;          // 0,4,8,12
  const int grow = block_m + arow;
  float acc[8][4] = {};

  for (int k0 = 0; k0 < HH; k0 += 16) {
    // stage A tile (64x16) as float4 per thread, transposed into As[k][m]
    float4 av = make_float4(0.f, 0.f, 0.f, 0.f);
    if (grow < NN) {
      av = *(const float4*)(A + (size_t)grow * HH + k0 + akq);
      if (RELU) {
        av.x = fmaxf(av.x, 0.f); av.y = fmaxf(av.y, 0.f);
        av.z = fmaxf(av.z, 0.f); av.w = fmaxf(av.w, 0.f);
      }
    }
    As[akq + 0][arow] = av.x;
    As[akq + 1][arow] = av.y;
    As[akq + 2][arow] = av.z;
    As[akq + 3][arow] = av.w;
    // stage W tile (16x128): 512 float4, 2 per thread
#pragma unroll
    for (int i = 0; i < 2; i++) {
      int f = t + i * 256;
      int k = f >> 5, nq = (f & 31) * 4;
      *(float4*)&Ws[k][nq] = *(const float4*)(W + (size_t)(k0 + k) * HH + nq);
    }
    __syncthreads();
#pragma unroll
    for (int k = 0; k < 16; k++) {
      float a[8], w[4];
#pragma unroll
      for (int i = 0; i < 8; i++) a[i] = As[k][tm * 8 + i];
#pragma unroll
      for (int j = 0; j < 4; j++) w[j] = Ws[k][tn * 4 + j];
#pragma unroll
      for (int i = 0; i < 8; i++)
#pragma unroll
        for (int j = 0; j < 4; j++) acc[i][j] += a[i] * w[j];
    }
    __syncthreads();
  }

  // epilogue: after final barrier all A-reads of this block's rows are done,
  // so writing Agg in-place over A is safe.
#pragma unroll
  for (int i = 0; i < 8; i++) {
    int gr = block_m + tm * 8 + i;
    if (gr < NN) {
      float dv = dinv[gr];
      float d2 = dv * dv;
#pragma unroll
      for (int j = 0; j < 4; j++) {
        int col = tn * 4 + j;
        float v = acc[i][j];
        Tm[(size_t)gr * HH + col] = v;
        Agg[(size_t)gr * HH + col] = d2 * v + b[col];
      }
    }
  }
}

// ---------------- edge scatter ----------------
// One 64-lane wave per edge; each lane handles 2 consecutive floats.
__global__ __launch_bounds__(256) void scatter_k(const int* __restrict__ ei,
                                                 const float* __restrict__ Tm,
                                                 const float* __restrict__ dinv,
                                                 float* __restrict__ Agg) {
  const int wave = threadIdx.x >> 6;  // 0..3
  const int lane = threadIdx.x & 63;
  const int e = blockIdx.x * 4 + wave;
  if (e >= EE) return;
  const int s = ei[e];
  const int d = ei[EE + e];
  const float norm = dinv[s] * dinv[d];
  float2 v = ((const float2*)(Tm + (size_t)s * HH))[lane];
  float* ap = Agg + (size_t)d * HH + lane * 2;
  atomicAdd(ap, v.x * norm);
  atomicAdd(ap + 1, v.y * norm);
}

// ---------------- pooling ----------------
__global__ __launch_bounds__(256) void pool_cnt_k(const int* __restrict__ batch,
                                                  float* __restrict__ cnt) {
  int n = blockIdx.x * 256 + threadIdx.x;
  if (n < NN) atomicAdd(&cnt[batch[n]], 1.0f);
}

__global__ __launch_bounds__(256) void pool_sum_k(const int* __restrict__ batch,
                                                  const float* __restrict__ h3,
                                                  float* __restrict__ pooled) {
  const int wave = threadIdx.x >> 6;
  const int lane = threadIdx.x & 63;
  const int n = blockIdx.x * 4 + wave;
  if (n >= NN) return;
  const int g = batch[n];
  float2 v = ((const float2*)(h3 + (size_t)n * HH))[lane];
  float* pp = pooled + (size_t)g * HH + lane * 2;
  atomicAdd(pp, v.x);
  atomicAdd(pp + 1, v.y);
}

// ---------------- final linear ----------------
__global__ __launch_bounds__(128) void final_k(const float* __restrict__ pooled,
                                               const float* __restrict__ cnt,
                                               const float* __restrict__ Wl,
                                               const float* __restrict__ bl,
                                               float* __restrict__ out) {
  const int g = blockIdx.x;
  const int t = threadIdx.x;
  __shared__ float p[128];
  const float inv = 1.0f / fmaxf(cnt[g], 1.0f);
  p[t] = pooled[(size_t)g * HH + t] * inv;
  __syncthreads();
  float acc = bl[t];
#pragma unroll 8
  for (int h = 0; h < HH; h++) acc += p[h] * Wl[h * TT + t];
  out[(size_t)g * TT + t] = acc;
}

extern "C" void kernel_launch(void* const* d_in, const int* in_sizes, int n_in,
                              void* d_out, int out_size, void* d_ws, size_t ws_size,
                              hipStream_t stream) {
  const int*   x     = (const int*)d_in[0];
  const int*   ei    = (const int*)d_in[1];
  const int*   batch = (const int*)d_in[2];
  const float* emb   = (const float*)d_in[3];
  const float* W1    = (const float*)d_in[4];
  const float* b1    = (const float*)d_in[5];
  const float* W2    = (const float*)d_in[6];
  const float* b2    = (const float*)d_in[7];
  const float* W3    = (const float*)d_in[8];
  const float* b3    = (const float*)d_in[9];
  const float* Wl    = (const float*)d_in[10];
  const float* bl    = (const float*)d_in[11];
  float* out = (float*)d_out;

  // workspace layout (~105 MB)
  float* bufH   = (float*)d_ws;                    // N*H  (h / agg, in-place)
  float* bufT   = bufH + (size_t)NN * HH;          // N*H  (t = h@W)
  float* dinv   = bufT + (size_t)NN * HH;          // N
  float* pooled = dinv + NN;                       // G*H
  float* cnt    = pooled + (size_t)GG * HH;        // G

  hipMemsetAsync(dinv, 0, NN * sizeof(float), stream);
  hipMemsetAsync(pooled, 0, (size_t)GG * HH * sizeof(float), stream);
  hipMemsetAsync(cnt, 0, GG * sizeof(float), stream);

  deg_count_k<<<(EE + 255) / 256, 256, 0, stream>>>(ei, dinv);
  dinv_k<<<(NN + 255) / 256, 256, 0, stream>>>(dinv);
  atom_enc_k<<<NN / 2, 256, 0, stream>>>(x, emb, bufH);

  const int gemm_grid = (NN + 63) / 64;
  const int scat_grid = (EE + 3) / 4;

  gemm_fused_k<false><<<gemm_grid, 256, 0, stream>>>(bufH, W1, b1, dinv, bufT, bufH);
  scatter_k<<<scat_grid, 256, 0, stream>>>(ei, bufT, dinv, bufH);

  gemm_fused_k<true><<<gemm_grid, 256, 0, stream>>>(bufH, W2, b2, dinv, bufT, bufH);
  scatter_k<<<scat_grid, 256, 0, stream>>>(ei, bufT, dinv, bufH);

  gemm_fused_k<true><<<gemm_grid, 256, 0, stream>>>(bufH, W3, b3, dinv, bufT, bufH);
  scatter_k<<<scat_grid, 256, 0, stream>>>(ei, bufT, dinv, bufH);

  pool_cnt_k<<<(NN + 255) / 256, 256, 0, stream>>>(batch, cnt);
  pool_sum_k<<<(NN + 3) / 4, 256, 0, stream>>>(batch, bufH, pooled);
  final_k<<<GG, 128, 0, stream>>>(pooled, cnt, Wl, bl, out);
}

// Round 2
// 546.375 us; speedup vs baseline: 3.4574x; 3.4574x over previous
//
#include <hip/hip_runtime.h>

#define NN 100000
#define EE 600000
#define HH 128
#define GG 4000
#define TT 128

// ---------------- degree count (int) ----------------
__global__ __launch_bounds__(256) void deg_count_k(const int* __restrict__ ei,
                                                   int* __restrict__ cnt) {
  int e = blockIdx.x * 256 + threadIdx.x;
  if (e < EE) atomicAdd(&cnt[ei[EE + e]], 1);   // dst row of edge_index
}

__global__ __launch_bounds__(256) void dinv_k(const int* __restrict__ cnt,
                                              float* __restrict__ dinv) {
  int n = blockIdx.x * 256 + threadIdx.x;
  if (n < NN) dinv[n] = rsqrtf((float)cnt[n] + 1.0f);   // +1 self-loop
}

// ---------------- CSR build: 3-kernel exclusive scan over cnt -> ptr ----------
__global__ __launch_bounds__(256) void scan1_k(const int* __restrict__ cnt,
                                               int* __restrict__ ptr,
                                               int* __restrict__ bsum) {
  const int i = blockIdx.x * 256 + threadIdx.x;
  int v = (i < NN) ? cnt[i] : 0;
  const int lane = threadIdx.x & 63, wid = threadIdx.x >> 6;
  int s = v;
#pragma unroll
  for (int off = 1; off < 64; off <<= 1) {
    int t = __shfl_up(s, off, 64);
    if (lane >= off) s += t;
  }
  __shared__ int wt[4];
  if (lane == 63) wt[wid] = s;
  __syncthreads();
  int wadd = 0;
  for (int w = 0; w < wid; w++) wadd += wt[w];
  int incl = s + wadd;
  if (i < NN) ptr[i] = incl - v;                 // exclusive within block
  if (threadIdx.x == 255) bsum[blockIdx.x] = incl;
}

__global__ __launch_bounds__(512) void scan2_k(int* __restrict__ bsum, int nb) {
  const int t = threadIdx.x;
  int v = (t < nb) ? bsum[t] : 0;
  const int lane = t & 63, wid = t >> 6;
  int s = v;
#pragma unroll
  for (int off = 1; off < 64; off <<= 1) {
    int u = __shfl_up(s, off, 64);
    if (lane >= off) s += u;
  }
  __shared__ int wt[8];
  if (lane == 63) wt[wid] = s;
  __syncthreads();
  int wadd = 0;
  for (int w = 0; w < wid; w++) wadd += wt[w];
  int incl = s + wadd;
  if (t < nb) bsum[t] = incl - v;                // exclusive block offsets
}

__global__ __launch_bounds__(256) void scan3_k(int* __restrict__ ptr,
                                               const int* __restrict__ bsum) {
  const int i = blockIdx.x * 256 + threadIdx.x;
  if (i < NN) ptr[i] += bsum[blockIdx.x];
  if (i == 0) ptr[NN] = EE;
}

// fill: cursor counts down via atomicSub on cnt (ends at 0, cnt dead after)
__global__ __launch_bounds__(256) void fill_k(const int* __restrict__ ei,
                                              const int* __restrict__ ptr,
                                              int* __restrict__ cnt,
                                              int* __restrict__ csr) {
  int e = blockIdx.x * 256 + threadIdx.x;
  if (e >= EE) return;
  int d = ei[EE + e];
  int ofs = atomicSub(&cnt[d], 1) - 1;           // count-1 .. 0
  csr[ptr[d] + ofs] = ei[e];                     // store src
}

// ---------------- atom encoder ----------------
__global__ __launch_bounds__(256) void atom_enc_k(const int* __restrict__ x,
                                                  const float* __restrict__ emb,
                                                  float* __restrict__ h0) {
  __shared__ int xs[2][9];
  const int local = threadIdx.x >> 7;   // 0..1
  const int lane  = threadIdx.x & 127;  // 0..127
  const int n = blockIdx.x * 2 + local; // grid = NN/2 exactly (NN even)
  if (lane < 9) xs[local][lane] = x[n * 9 + lane];
  __syncthreads();
  const int off[9] = {0, 119, 124, 136, 148, 158, 164, 170, 172};
  float s = 0.0f;
#pragma unroll
  for (int f = 0; f < 9; f++)
    s += emb[(size_t)(xs[local][f] + off[f]) * HH + lane];
  h0[(size_t)n * HH + lane] = s;
}

// ---------------- fused GEMM + self-loop/bias epilogue ----------------
// Tm  = dinv * ((RELU? relu(A) : A) @ W)      [N,H]  (pre-scaled messages)
// Agg = dinv * Tm + b                          [N,H]  (= dinv^2 * t + b)
// may alias A: each block reads only its own 64 rows before the last barrier.
template <bool RELU>
__global__ __launch_bounds__(256) void gemm_fused_k(const float* __restrict__ A,
                                                    const float* __restrict__ W,
                                                    const float* __restrict__ b,
                                                    const float* __restrict__ dinv,
                                                    float* __restrict__ Tm,
                                                    float* __restrict__ Agg) {
  __shared__ float As[16][64];    // [k][m]
  __shared__ float Ws[16][128];   // [k][n]
  const int t = threadIdx.x;
  const int block_m = blockIdx.x * 64;
  const int tm = t >> 5;                 // 0..7 -> rows tm*8..tm*8+7
  const int tn = t & 31;                 // 0..31 -> cols tn*4..tn*4+3
  const int arow = t >> 2;               // 0..63
  const int akq  = (t & 3) * 4;          // 0,4,8,12
  const int grow = block_m + arow;
  float acc[8][4] = {};

  for (int k0 = 0; k0 < HH; k0 += 16) {
    float4 av = make_float4(0.f, 0.f, 0.f, 0.f);
    if (grow < NN) {
      av = *(const float4*)(A + (size_t)grow * HH + k0 + akq);
      if (RELU) {
        av.x = fmaxf(av.x, 0.f); av.y = fmaxf(av.y, 0.f);
        av.z = fmaxf(av.z, 0.f); av.w = fmaxf(av.w, 0.f);
      }
    }
    As[akq + 0][arow] = av.x;
    As[akq + 1][arow] = av.y;
    As[akq + 2][arow] = av.z;
    As[akq + 3][arow] = av.w;
#pragma unroll
    for (int i = 0; i < 2; i++) {
      int f = t + i * 256;
      int k = f >> 5, nq = (f & 31) * 4;
      *(float4*)&Ws[k][nq] = *(const float4*)(W + (size_t)(k0 + k) * HH + nq);
    }
    __syncthreads();
#pragma unroll
    for (int k = 0; k < 16; k++) {
      float a[8], w[4];
#pragma unroll
      for (int i = 0; i < 8; i++) a[i] = As[k][tm * 8 + i];
#pragma unroll
      for (int j = 0; j < 4; j++) w[j] = Ws[k][tn * 4 + j];
#pragma unroll
      for (int i = 0; i < 8; i++)
#pragma unroll
        for (int j = 0; j < 4; j++) acc[i][j] += a[i] * w[j];
    }
    __syncthreads();
  }

#pragma unroll
  for (int i = 0; i < 8; i++) {
    int gr = block_m + tm * 8 + i;
    if (gr < NN) {
      float dv = dinv[gr];
#pragma unroll
      for (int j = 0; j < 4; j++) {
        int col = tn * 4 + j;
        float tv = dv * acc[i][j];               // pre-scaled message
        Tm[(size_t)gr * HH + col] = tv;
        Agg[(size_t)gr * HH + col] = dv * tv + b[col];
      }
    }
  }
}

// ---------------- CSR aggregation (owner-computes, no atomics) ----------------
// Agg[n] += dinv[n] * sum_{s in in(n)} Tm[s]   (Tm pre-scaled by dinv[s])
__global__ __launch_bounds__(256) void agg_k(const int* __restrict__ ptr,
                                             const int* __restrict__ csr,
                                             const float* __restrict__ Tm,
                                             const float* __restrict__ dinv,
                                             float* __restrict__ Agg) {
  const int wave = threadIdx.x >> 6;
  const int lane = threadIdx.x & 63;
  const int n = blockIdx.x * 4 + wave;
  if (n >= NN) return;
  const int beg = ptr[n], end = ptr[n + 1];
  float2 acc = make_float2(0.f, 0.f);
  int i = beg;
  for (; i + 1 < end; i += 2) {
    int s0 = csr[i], s1 = csr[i + 1];
    float2 v0 = ((const float2*)(Tm + (size_t)s0 * HH))[lane];
    float2 v1 = ((const float2*)(Tm + (size_t)s1 * HH))[lane];
    acc.x += v0.x + v1.x;
    acc.y += v0.y + v1.y;
  }
  if (i < end) {
    int s0 = csr[i];
    float2 v0 = ((const float2*)(Tm + (size_t)s0 * HH))[lane];
    acc.x += v0.x;
    acc.y += v0.y;
  }
  const float dv = dinv[n];
  float2* ap = (float2*)(Agg + (size_t)n * HH) + lane;
  float2 cur = *ap;
  cur.x += dv * acc.x;
  cur.y += dv * acc.y;
  *ap = cur;
}

// ---------------- pooling: batch is sorted -> binary-search ranges ------------
__device__ inline int lbound(const int* __restrict__ b, int val) {
  int lo = 0, hi = NN;
  while (lo < hi) {
    int mid = (lo + hi) >> 1;
    if (b[mid] < val) lo = mid + 1; else hi = mid;
  }
  return lo;
}

__global__ __launch_bounds__(256) void pool_k(const int* __restrict__ batch,
                                              const float* __restrict__ h3,
                                              float* __restrict__ pooled) {
  const int wave = threadIdx.x >> 6;
  const int lane = threadIdx.x & 63;
  const int g = blockIdx.x * 4 + wave;
  if (g >= GG) return;
  const int beg = lbound(batch, g);
  const int end = lbound(batch, g + 1);
  float2 acc = make_float2(0.f, 0.f);
  for (int n = beg; n < end; n++) {
    float2 v = ((const float2*)(h3 + (size_t)n * HH))[lane];
    acc.x += v.x; acc.y += v.y;
  }
  const float inv = 1.0f / (float)max(end - beg, 1);
  ((float2*)(pooled + (size_t)g * HH))[lane] = make_float2(acc.x * inv, acc.y * inv);
}

// ---------------- final linear ----------------
__global__ __launch_bounds__(128) void final_k(const float* __restrict__ pooled,
                                               const float* __restrict__ Wl,
                                               const float* __restrict__ bl,
                                               float* __restrict__ out) {
  const int g = blockIdx.x;
  const int t = threadIdx.x;
  __shared__ float p[128];
  p[t] = pooled[(size_t)g * HH + t];
  __syncthreads();
  float acc = bl[t];
#pragma unroll 8
  for (int h = 0; h < HH; h++) acc += p[h] * Wl[h * TT + t];
  out[(size_t)g * TT + t] = acc;
}

extern "C" void kernel_launch(void* const* d_in, const int* in_sizes, int n_in,
                              void* d_out, int out_size, void* d_ws, size_t ws_size,
                              hipStream_t stream) {
  const int*   x     = (const int*)d_in[0];
  const int*   ei    = (const int*)d_in[1];
  const int*   batch = (const int*)d_in[2];
  const float* emb   = (const float*)d_in[3];
  const float* W1    = (const float*)d_in[4];
  const float* b1    = (const float*)d_in[5];
  const float* W2    = (const float*)d_in[6];
  const float* b2    = (const float*)d_in[7];
  const float* W3    = (const float*)d_in[8];
  const float* b3    = (const float*)d_in[9];
  const float* Wl    = (const float*)d_in[10];
  const float* bl    = (const float*)d_in[11];
  float* out = (float*)d_out;

  // workspace layout (~106 MB)
  float* bufH   = (float*)d_ws;                    // N*H (h / agg, in-place)
  float* bufT   = bufH + (size_t)NN * HH;          // N*H (Tm, pre-scaled)
  float* dinv   = bufT + (size_t)NN * HH;          // N
  int*   ptr    = (int*)(dinv + NN);               // N+1
  int*   cnt    = ptr + NN + 1;                    // N (count, then fill cursor)
  int*   bsum   = cnt + NN;                        // 512
  int*   csr    = bsum + 512;                      // E (src per edge, dst-sorted)
  float* pooled = bufT;                            // G*H (bufT dead after agg3)

  hipMemsetAsync(cnt, 0, NN * sizeof(int), stream);

  const int NB = (NN + 255) / 256;                 // 391 scan blocks

  deg_count_k<<<(EE + 255) / 256, 256, 0, stream>>>(ei, cnt);
  dinv_k<<<NB, 256, 0, stream>>>(cnt, dinv);
  scan1_k<<<NB, 256, 0, stream>>>(cnt, ptr, bsum);
  scan2_k<<<1, 512, 0, stream>>>(bsum, NB);
  scan3_k<<<NB, 256, 0, stream>>>(ptr, bsum);
  fill_k<<<(EE + 255) / 256, 256, 0, stream>>>(ei, ptr, cnt, csr);

  atom_enc_k<<<NN / 2, 256, 0, stream>>>(x, emb, bufH);

  const int gemm_grid = (NN + 63) / 64;
  const int agg_grid  = (NN + 3) / 4;

  gemm_fused_k<false><<<gemm_grid, 256, 0, stream>>>(bufH, W1, b1, dinv, bufT, bufH);
  agg_k<<<agg_grid, 256, 0, stream>>>(ptr, csr, bufT, dinv, bufH);

  gemm_fused_k<true><<<gemm_grid, 256, 0, stream>>>(bufH, W2, b2, dinv, bufT, bufH);
  agg_k<<<agg_grid, 256, 0, stream>>>(ptr, csr, bufT, dinv, bufH);

  gemm_fused_k<true><<<gemm_grid, 256, 0, stream>>>(bufH, W3, b3, dinv, bufT, bufH);
  agg_k<<<agg_grid, 256, 0, stream>>>(ptr, csr, bufT, dinv, bufH);

  pool_k<<<(GG + 3) / 4, 256, 0, stream>>>(batch, bufH, pooled);
  final_k<<<GG, 128, 0, stream>>>(pooled, Wl, bl, out);
}

// Round 3
// 453.418 us; speedup vs baseline: 4.1662x; 1.2050x over previous
//
#include <hip/hip_runtime.h>

#define NN 100000
#define EE 600000
#define HH 128
#define GG 4000
#define TT 128

typedef short short8 __attribute__((ext_vector_type(8)));
typedef float floatx4 __attribute__((ext_vector_type(4)));

static __device__ __forceinline__ float bf2f(unsigned short u) {
  union { unsigned int i; float f; } v; v.i = ((unsigned int)u) << 16; return v.f;
}
static __device__ __forceinline__ unsigned short f2bf(float f) {
  union { float f; unsigned int i; } v; v.f = f;
  unsigned int r = (v.i + 0x7FFFu + ((v.i >> 16) & 1u)) >> 16;   // RNE
  return (unsigned short)r;
}

// ---------------- degree count (int) ----------------
__global__ __launch_bounds__(256) void deg_count_k(const int* __restrict__ ei,
                                                   int* __restrict__ cnt) {
  int e = blockIdx.x * 256 + threadIdx.x;
  if (e < EE) atomicAdd(&cnt[ei[EE + e]], 1);   // dst row
}

__global__ __launch_bounds__(256) void dinv_k(const int* __restrict__ cnt,
                                              float* __restrict__ dinv) {
  int n = blockIdx.x * 256 + threadIdx.x;
  if (n < NN) dinv[n] = rsqrtf((float)cnt[n] + 1.0f);   // +1 self-loop
}

// ---------------- CSR build: 3-kernel exclusive scan ----------------
__global__ __launch_bounds__(256) void scan1_k(const int* __restrict__ cnt,
                                               int* __restrict__ ptr,
                                               int* __restrict__ bsum) {
  const int i = blockIdx.x * 256 + threadIdx.x;
  int v = (i < NN) ? cnt[i] : 0;
  const int lane = threadIdx.x & 63, wid = threadIdx.x >> 6;
  int s = v;
#pragma unroll
  for (int off = 1; off < 64; off <<= 1) {
    int t = __shfl_up(s, off, 64);
    if (lane >= off) s += t;
  }
  __shared__ int wt[4];
  if (lane == 63) wt[wid] = s;
  __syncthreads();
  int wadd = 0;
  for (int w = 0; w < wid; w++) wadd += wt[w];
  int incl = s + wadd;
  if (i < NN) ptr[i] = incl - v;
  if (threadIdx.x == 255) bsum[blockIdx.x] = incl;
}

__global__ __launch_bounds__(512) void scan2_k(int* __restrict__ bsum, int nb) {
  const int t = threadIdx.x;
  int v = (t < nb) ? bsum[t] : 0;
  const int lane = t & 63, wid = t >> 6;
  int s = v;
#pragma unroll
  for (int off = 1; off < 64; off <<= 1) {
    int u = __shfl_up(s, off, 64);
    if (lane >= off) s += u;
  }
  __shared__ int wt[8];
  if (lane == 63) wt[wid] = s;
  __syncthreads();
  int wadd = 0;
  for (int w = 0; w < wid; w++) wadd += wt[w];
  int incl = s + wadd;
  if (t < nb) bsum[t] = incl - v;
}

__global__ __launch_bounds__(256) void scan3_k(int* __restrict__ ptr,
                                               const int* __restrict__ bsum) {
  const int i = blockIdx.x * 256 + threadIdx.x;
  if (i < NN) ptr[i] += bsum[blockIdx.x];
  if (i == 0) ptr[NN] = EE;
}

__global__ __launch_bounds__(256) void fill_k(const int* __restrict__ ei,
                                              const int* __restrict__ ptr,
                                              int* __restrict__ cnt,
                                              int* __restrict__ csr) {
  int e = blockIdx.x * 256 + threadIdx.x;
  if (e >= EE) return;
  int d = ei[EE + e];
  int ofs = atomicSub(&cnt[d], 1) - 1;
  csr[ptr[d] + ofs] = ei[e];                     // store src
}

// ---------------- atom encoder (bf16 out) ----------------
__global__ __launch_bounds__(256) void atom_enc_k(const int* __restrict__ x,
                                                  const float* __restrict__ emb,
                                                  unsigned short* __restrict__ h0) {
  __shared__ int xs[2][9];
  const int local = threadIdx.x >> 7;
  const int lane  = threadIdx.x & 127;
  const int n = blockIdx.x * 2 + local;   // NN even
  if (lane < 9) xs[local][lane] = x[n * 9 + lane];
  __syncthreads();
  const int off[9] = {0, 119, 124, 136, 148, 158, 164, 170, 172};
  float s = 0.0f;
#pragma unroll
  for (int f = 0; f < 9; f++)
    s += emb[(size_t)(xs[local][f] + off[f]) * HH + lane];
  h0[(size_t)n * HH + lane] = f2bf(s);
}

// ---------------- weight transpose+convert: Wt[n][k] = bf16(W[k][n]) --------
__global__ __launch_bounds__(128) void wtconv_k(const float* __restrict__ W,
                                                unsigned short* __restrict__ Wt) {
  const int n = blockIdx.x, k = threadIdx.x;
  Wt[n * HH + k] = f2bf(W[k * HH + n]);
}

// ---------------- MFMA GEMM + self-loop epilogue ----------------
// Tm  = bf16(dinv * (A @ W))          (pre-scaled messages)
// Agg = bf16(dinv * Tm + b)           (may alias A: per-wave own rows only)
__global__ __launch_bounds__(256) void gemm_mfma_k(const unsigned short* __restrict__ A,
                                                   const unsigned short* __restrict__ Wt,
                                                   const float* __restrict__ b,
                                                   const float* __restrict__ dinv,
                                                   unsigned short* __restrict__ Tm,
                                                   unsigned short* __restrict__ Agg) {
  const int w = threadIdx.x >> 6;
  const int l = threadIdx.x & 63;
  const int m16 = l & 15;              // row-in-tile (A) / col-in-tile (B, C)
  const int q8  = (l >> 4) * 8;        // k-offset of this lane's 8 elements
  const int bm  = blockIdx.x * 128 + w * 32;

  floatx4 acc[2][8];
#pragma unroll
  for (int i = 0; i < 2; i++)
#pragma unroll
    for (int j = 0; j < 8; j++) acc[i][j] = (floatx4){0.f, 0.f, 0.f, 0.f};

  for (int q = 0; q < 4; q++) {        // K = 128 in steps of 32
    const int k0 = q * 32;
    short8 a[2];
#pragma unroll
    for (int ti = 0; ti < 2; ti++) {
      int row = bm + ti * 16 + m16;
      a[ti] = (row < NN) ? *(const short8*)(A + (size_t)row * HH + k0 + q8)
                         : (short8){0, 0, 0, 0, 0, 0, 0, 0};
    }
#pragma unroll
    for (int tn = 0; tn < 8; tn++) {
      short8 bf = *(const short8*)(Wt + (size_t)(tn * 16 + m16) * HH + k0 + q8);
      acc[0][tn] = __builtin_amdgcn_mfma_f32_16x16x32_bf16(a[0], bf, acc[0][tn], 0, 0, 0);
      acc[1][tn] = __builtin_amdgcn_mfma_f32_16x16x32_bf16(a[1], bf, acc[1][tn], 0, 0, 0);
    }
  }

  float bias[8];
#pragma unroll
  for (int tn = 0; tn < 8; tn++) bias[tn] = b[tn * 16 + m16];

#pragma unroll
  for (int ti = 0; ti < 2; ti++) {
    const int rbase = bm + ti * 16 + (l >> 4) * 4;
#pragma unroll
    for (int r = 0; r < 4; r++) {
      const int row = rbase + r;
      if (row < NN) {
        const float dv = dinv[row];
#pragma unroll
        for (int tn = 0; tn < 8; tn++) {
          const int col = tn * 16 + m16;
          float tv = dv * acc[ti][tn][r];
          Tm[(size_t)row * HH + col]  = f2bf(tv);
          Agg[(size_t)row * HH + col] = f2bf(dv * tv + bias[tn]);
        }
      }
    }
  }
}

// ---------------- CSR aggregation (bf16 gather, fp32 accum) ----------------
// Hout[n] = (relu?)( AggIn[n] + dinv[n] * sum_{s in in(n)} Tm[s] )
template <bool RELU>
__global__ __launch_bounds__(256) void agg_bf_k(const int* __restrict__ ptr,
                                                const int* __restrict__ csr,
                                                const unsigned short* __restrict__ Tm,
                                                const float* __restrict__ dinv,
                                                const unsigned short* __restrict__ AggIn,
                                                unsigned short* __restrict__ Hout) {
  const int wave = threadIdx.x >> 6;
  const int lane = threadIdx.x & 63;
  const int n = blockIdx.x * 4 + wave;
  if (n >= NN) return;
  const int beg = ptr[n], end = ptr[n + 1];
  float ax = 0.f, ay = 0.f;
  int i = beg;
  for (; i + 3 < end; i += 4) {
    int s0 = csr[i], s1 = csr[i + 1], s2 = csr[i + 2], s3 = csr[i + 3];
    ushort2 v0 = ((const ushort2*)(Tm + (size_t)s0 * HH))[lane];
    ushort2 v1 = ((const ushort2*)(Tm + (size_t)s1 * HH))[lane];
    ushort2 v2 = ((const ushort2*)(Tm + (size_t)s2 * HH))[lane];
    ushort2 v3 = ((const ushort2*)(Tm + (size_t)s3 * HH))[lane];
    ax += bf2f(v0.x) + bf2f(v1.x) + bf2f(v2.x) + bf2f(v3.x);
    ay += bf2f(v0.y) + bf2f(v1.y) + bf2f(v2.y) + bf2f(v3.y);
  }
  for (; i < end; i++) {
    int s0 = csr[i];
    ushort2 v0 = ((const ushort2*)(Tm + (size_t)s0 * HH))[lane];
    ax += bf2f(v0.x);
    ay += bf2f(v0.y);
  }
  const float dv = dinv[n];
  ushort2 cur = ((const ushort2*)(AggIn + (size_t)n * HH))[lane];
  float ox = bf2f(cur.x) + dv * ax;
  float oy = bf2f(cur.y) + dv * ay;
  if (RELU) { ox = fmaxf(ox, 0.f); oy = fmaxf(oy, 0.f); }
  ushort2 o; o.x = f2bf(ox); o.y = f2bf(oy);
  ((ushort2*)(Hout + (size_t)n * HH))[lane] = o;
}

// ---------------- pooling: batch sorted -> binary-search ranges -------------
__device__ inline int lbound(const int* __restrict__ b, int val) {
  int lo = 0, hi = NN;
  while (lo < hi) {
    int mid = (lo + hi) >> 1;
    if (b[mid] < val) lo = mid + 1; else hi = mid;
  }
  return lo;
}

__global__ __launch_bounds__(256) void pool_k(const int* __restrict__ batch,
                                              const unsigned short* __restrict__ h3,
                                              float* __restrict__ pooled) {
  const int wave = threadIdx.x >> 6;
  const int lane = threadIdx.x & 63;
  const int g = blockIdx.x * 4 + wave;
  if (g >= GG) return;
  const int beg = lbound(batch, g);
  const int end = lbound(batch, g + 1);
  float ax = 0.f, ay = 0.f;
  for (int n = beg; n < end; n++) {
    ushort2 v = ((const ushort2*)(h3 + (size_t)n * HH))[lane];
    ax += bf2f(v.x); ay += bf2f(v.y);
  }
  const float inv = 1.0f / (float)max(end - beg, 1);
  ((float2*)(pooled + (size_t)g * HH))[lane] = make_float2(ax * inv, ay * inv);
}

// ---------------- final linear ----------------
__global__ __launch_bounds__(128) void final_k(const float* __restrict__ pooled,
                                               const float* __restrict__ Wl,
                                               const float* __restrict__ bl,
                                               float* __restrict__ out) {
  const int g = blockIdx.x;
  const int t = threadIdx.x;
  __shared__ float p[128];
  p[t] = pooled[(size_t)g * HH + t];
  __syncthreads();
  float acc = bl[t];
#pragma unroll 8
  for (int h = 0; h < HH; h++) acc += p[h] * Wl[h * TT + t];
  out[(size_t)g * TT + t] = acc;
}

extern "C" void kernel_launch(void* const* d_in, const int* in_sizes, int n_in,
                              void* d_out, int out_size, void* d_ws, size_t ws_size,
                              hipStream_t stream) {
  const int*   x     = (const int*)d_in[0];
  const int*   ei    = (const int*)d_in[1];
  const int*   batch = (const int*)d_in[2];
  const float* emb   = (const float*)d_in[3];
  const float* W1    = (const float*)d_in[4];
  const float* b1    = (const float*)d_in[5];
  const float* W2    = (const float*)d_in[6];
  const float* b2    = (const float*)d_in[7];
  const float* W3    = (const float*)d_in[8];
  const float* b3    = (const float*)d_in[9];
  const float* Wl    = (const float*)d_in[10];
  const float* bl    = (const float*)d_in[11];
  float* out = (float*)d_out;

  // workspace layout (~57 MB)
  unsigned short* bufA = (unsigned short*)d_ws;        // N*H bf16 (h / agg, in-place)
  unsigned short* bufT = bufA + (size_t)NN * HH;       // N*H bf16 (Tm)
  unsigned short* Wt   = bufT + (size_t)NN * HH;       // 3*H*H bf16
  float* dinv   = (float*)(Wt + 3 * HH * HH);          // N
  int*   ptr    = (int*)(dinv + NN);                   // N+1
  int*   cnt    = ptr + NN + 1;                        // N
  int*   bsum   = cnt + NN;                            // 512
  int*   csr    = bsum + 512;                          // E
  float* pooled = (float*)(csr + EE);                  // G*H

  hipMemsetAsync(cnt, 0, NN * sizeof(int), stream);

  const int NB = (NN + 255) / 256;

  deg_count_k<<<(EE + 255) / 256, 256, 0, stream>>>(ei, cnt);
  dinv_k<<<NB, 256, 0, stream>>>(cnt, dinv);
  scan1_k<<<NB, 256, 0, stream>>>(cnt, ptr, bsum);
  scan2_k<<<1, 512, 0, stream>>>(bsum, NB);
  scan3_k<<<NB, 256, 0, stream>>>(ptr, bsum);
  fill_k<<<(EE + 255) / 256, 256, 0, stream>>>(ei, ptr, cnt, csr);

  atom_enc_k<<<NN / 2, 256, 0, stream>>>(x, emb, bufA);
  wtconv_k<<<HH, HH, 0, stream>>>(W1, Wt);
  wtconv_k<<<HH, HH, 0, stream>>>(W2, Wt + HH * HH);
  wtconv_k<<<HH, HH, 0, stream>>>(W3, Wt + 2 * HH * HH);

  const int gemm_grid = (NN + 127) / 128;
  const int agg_grid  = (NN + 3) / 4;

  gemm_mfma_k<<<gemm_grid, 256, 0, stream>>>(bufA, Wt, b1, dinv, bufT, bufA);
  agg_bf_k<true><<<agg_grid, 256, 0, stream>>>(ptr, csr, bufT, dinv, bufA, bufA);

  gemm_mfma_k<<<gemm_grid, 256, 0, stream>>>(bufA, Wt + HH * HH, b2, dinv, bufT, bufA);
  agg_bf_k<true><<<agg_grid, 256, 0, stream>>>(ptr, csr, bufT, dinv, bufA, bufA);

  gemm_mfma_k<<<gemm_grid, 256, 0, stream>>>(bufA, Wt + 2 * HH * HH, b3, dinv, bufT, bufA);
  agg_bf_k<false><<<agg_grid, 256, 0, stream>>>(ptr, csr, bufT, dinv, bufA, bufA);

  pool_k<<<(GG + 3) / 4, 256, 0, stream>>>(batch, bufA, pooled);
  final_k<<<GG, 128, 0, stream>>>(pooled, Wl, bl, out);
}

// Round 4
// 390.022 us; speedup vs baseline: 4.8434x; 1.1625x over previous
//
#include <hip/hip_runtime.h>

#define NN 100000
#define EE 600000
#define HH 128
#define GG 4000
#define TT 128

typedef short short8 __attribute__((ext_vector_type(8)));
typedef unsigned short ushort8v __attribute__((ext_vector_type(8)));
typedef float floatx4 __attribute__((ext_vector_type(4)));

static __device__ __forceinline__ float bf2f(unsigned short u) {
  union { unsigned int i; float f; } v; v.i = ((unsigned int)u) << 16; return v.f;
}
static __device__ __forceinline__ unsigned short f2bf(float f) {
  union { float f; unsigned int i; } v; v.f = f;
  unsigned int r = (v.i + 0x7FFFu + ((v.i >> 16) & 1u)) >> 16;   // RNE
  return (unsigned short)r;
}

// ---------------- degree count (int) ----------------
__global__ __launch_bounds__(256) void deg_count_k(const int* __restrict__ ei,
                                                   int* __restrict__ cnt) {
  int e = blockIdx.x * 256 + threadIdx.x;
  if (e < EE) atomicAdd(&cnt[ei[EE + e]], 1);   // dst row
}

// ---------------- CSR build: 3-kernel exclusive scan (+dinv fused) ----------
__global__ __launch_bounds__(256) void scan1_k(const int* __restrict__ cnt,
                                               int* __restrict__ ptr,
                                               int* __restrict__ bsum,
                                               float* __restrict__ dinv) {
  const int i = blockIdx.x * 256 + threadIdx.x;
  int v = (i < NN) ? cnt[i] : 0;
  if (i < NN) dinv[i] = rsqrtf((float)v + 1.0f);   // +1 self-loop
  const int lane = threadIdx.x & 63, wid = threadIdx.x >> 6;
  int s = v;
#pragma unroll
  for (int off = 1; off < 64; off <<= 1) {
    int t = __shfl_up(s, off, 64);
    if (lane >= off) s += t;
  }
  __shared__ int wt[4];
  if (lane == 63) wt[wid] = s;
  __syncthreads();
  int wadd = 0;
  for (int w = 0; w < wid; w++) wadd += wt[w];
  int incl = s + wadd;
  if (i < NN) ptr[i] = incl - v;
  if (threadIdx.x == 255) bsum[blockIdx.x] = incl;
}

__global__ __launch_bounds__(512) void scan2_k(int* __restrict__ bsum, int nb) {
  const int t = threadIdx.x;
  int v = (t < nb) ? bsum[t] : 0;
  const int lane = t & 63, wid = t >> 6;
  int s = v;
#pragma unroll
  for (int off = 1; off < 64; off <<= 1) {
    int u = __shfl_up(s, off, 64);
    if (lane >= off) s += u;
  }
  __shared__ int wt[8];
  if (lane == 63) wt[wid] = s;
  __syncthreads();
  int wadd = 0;
  for (int w = 0; w < wid; w++) wadd += wt[w];
  int incl = s + wadd;
  if (t < nb) bsum[t] = incl - v;
}

__global__ __launch_bounds__(256) void scan3_k(int* __restrict__ ptr,
                                               const int* __restrict__ bsum) {
  const int i = blockIdx.x * 256 + threadIdx.x;
  if (i < NN) ptr[i] += bsum[blockIdx.x];
  if (i == 0) ptr[NN] = EE;
}

__global__ __launch_bounds__(256) void fill_k(const int* __restrict__ ei,
                                              const int* __restrict__ ptr,
                                              int* __restrict__ cnt,
                                              int* __restrict__ csr) {
  int e = blockIdx.x * 256 + threadIdx.x;
  if (e >= EE) return;
  int d = ei[EE + e];
  int ofs = atomicSub(&cnt[d], 1) - 1;
  csr[ptr[d] + ofs] = ei[e];                     // store src
}

// ---------------- atom encoder (16 lanes/node, ushort8 stores) --------------
__global__ __launch_bounds__(256) void atom_enc_k(const int* __restrict__ x,
                                                  const float* __restrict__ emb,
                                                  unsigned short* __restrict__ h0) {
  const int lane = threadIdx.x & 63;
  const int wid  = threadIdx.x >> 6;
  const int l16  = lane & 15;
  const int n = blockIdx.x * 16 + wid * 4 + (lane >> 4);   // grid*16 == NN
  const int off[9] = {0, 119, 124, 136, 148, 158, 164, 170, 172};
  int xv = (l16 < 9) ? x[n * 9 + l16] : 0;
  float s[8] = {0.f, 0.f, 0.f, 0.f, 0.f, 0.f, 0.f, 0.f};
#pragma unroll
  for (int f = 0; f < 9; f++) {
    int idx = __shfl(xv, (lane & 48) | f, 64) + off[f];
    const float* ep = emb + (size_t)idx * HH + l16 * 8;
    float4 e0 = *(const float4*)ep;
    float4 e1 = *(const float4*)(ep + 4);
    s[0] += e0.x; s[1] += e0.y; s[2] += e0.z; s[3] += e0.w;
    s[4] += e1.x; s[5] += e1.y; s[6] += e1.z; s[7] += e1.w;
  }
  ushort8v o;
#pragma unroll
  for (int j = 0; j < 8; j++) o[j] = f2bf(s[j]);
  *(ushort8v*)(h0 + (size_t)n * HH + l16 * 8) = o;
}

// ---------------- weight transpose+convert: Wt[n][k] = bf16(W[k][n]) --------
__global__ __launch_bounds__(128) void wtconv_k(const float* __restrict__ W,
                                                unsigned short* __restrict__ Wt) {
  const int n = blockIdx.x, k = threadIdx.x;
  Wt[n * HH + k] = f2bf(W[k * HH + n]);
}

// ---------------- MFMA GEMM + self-loop epilogue ----------------
// Tm  = bf16(dinv * (A @ W))          (pre-scaled messages)
// Agg = bf16(dinv * Tm + b)           (may alias A: per-wave own rows only)
__global__ __launch_bounds__(256) void gemm_mfma_k(const unsigned short* __restrict__ A,
                                                   const unsigned short* __restrict__ Wt,
                                                   const float* __restrict__ b,
                                                   const float* __restrict__ dinv,
                                                   unsigned short* __restrict__ Tm,
                                                   unsigned short* __restrict__ Agg) {
  const int w = threadIdx.x >> 6;
  const int l = threadIdx.x & 63;
  const int m16 = l & 15;              // row-in-tile (A) / col-in-tile (B, C)
  const int q8  = (l >> 4) * 8;        // k-offset of this lane's 8 elements
  const int bm  = blockIdx.x * 128 + w * 32;

  floatx4 acc[2][8];
#pragma unroll
  for (int i = 0; i < 2; i++)
#pragma unroll
    for (int j = 0; j < 8; j++) acc[i][j] = (floatx4){0.f, 0.f, 0.f, 0.f};

  for (int q = 0; q < 4; q++) {        // K = 128 in steps of 32
    const int k0 = q * 32;
    short8 a[2];
#pragma unroll
    for (int ti = 0; ti < 2; ti++) {
      int row = bm + ti * 16 + m16;
      a[ti] = (row < NN) ? *(const short8*)(A + (size_t)row * HH + k0 + q8)
                         : (short8){0, 0, 0, 0, 0, 0, 0, 0};
    }
#pragma unroll
    for (int tn = 0; tn < 8; tn++) {
      short8 bf = *(const short8*)(Wt + (size_t)(tn * 16 + m16) * HH + k0 + q8);
      acc[0][tn] = __builtin_amdgcn_mfma_f32_16x16x32_bf16(a[0], bf, acc[0][tn], 0, 0, 0);
      acc[1][tn] = __builtin_amdgcn_mfma_f32_16x16x32_bf16(a[1], bf, acc[1][tn], 0, 0, 0);
    }
  }

  float bias[8];
#pragma unroll
  for (int tn = 0; tn < 8; tn++) bias[tn] = b[tn * 16 + m16];

#pragma unroll
  for (int ti = 0; ti < 2; ti++) {
    const int rbase = bm + ti * 16 + (l >> 4) * 4;
#pragma unroll
    for (int r = 0; r < 4; r++) {
      const int row = rbase + r;
      if (row < NN) {
        const float dv = dinv[row];
#pragma unroll
        for (int tn = 0; tn < 8; tn++) {
          const int col = tn * 16 + m16;
          float tv = dv * acc[ti][tn][r];
          Tm[(size_t)row * HH + col]  = f2bf(tv);
          Agg[(size_t)row * HH + col] = f2bf(dv * tv + bias[tn]);
        }
      }
    }
  }
}

// ---------------- CSR aggregation: 16 lanes/node, 4 nodes/wave --------------
// Hout[n] = (relu?)( AggIn[n] + dinv[n] * sum_{s in in(n)} Tm[s] )
template <bool RELU>
__global__ __launch_bounds__(256) void agg_bf_k(const int* __restrict__ ptr,
                                                const int* __restrict__ csr,
                                                const unsigned short* __restrict__ Tm,
                                                const float* __restrict__ dinv,
                                                const unsigned short* __restrict__ AggIn,
                                                unsigned short* __restrict__ Hout) {
  const int lane = threadIdx.x & 63;
  const int wid  = threadIdx.x >> 6;
  const int l16  = lane & 15;
  const int n = blockIdx.x * 16 + wid * 4 + (lane >> 4);   // grid*16 == NN
  const int beg = ptr[n], end = ptr[n + 1];
  float acc[8] = {0.f, 0.f, 0.f, 0.f, 0.f, 0.f, 0.f, 0.f};
  int i = beg;
  for (; i + 1 < end; i += 2) {
    int s0 = csr[i], s1 = csr[i + 1];
    ushort8v v0 = *(const ushort8v*)(Tm + (size_t)s0 * HH + l16 * 8);
    ushort8v v1 = *(const ushort8v*)(Tm + (size_t)s1 * HH + l16 * 8);
#pragma unroll
    for (int j = 0; j < 8; j++) acc[j] += bf2f(v0[j]) + bf2f(v1[j]);
  }
  if (i < end) {
    int s0 = csr[i];
    ushort8v v0 = *(const ushort8v*)(Tm + (size_t)s0 * HH + l16 * 8);
#pragma unroll
    for (int j = 0; j < 8; j++) acc[j] += bf2f(v0[j]);
  }
  const float dv = dinv[n];
  ushort8v cur = *(const ushort8v*)(AggIn + (size_t)n * HH + l16 * 8);
  ushort8v o;
#pragma unroll
  for (int j = 0; j < 8; j++) {
    float v = bf2f(cur[j]) + dv * acc[j];
    if (RELU) v = fmaxf(v, 0.f);
    o[j] = f2bf(v);
  }
  *(ushort8v*)(Hout + (size_t)n * HH + l16 * 8) = o;
}

// ---------------- fused pool + final linear ----------------
__device__ inline int lbound(const int* __restrict__ b, int val) {
  int lo = 0, hi = NN;
  while (lo < hi) {
    int mid = (lo + hi) >> 1;
    if (b[mid] < val) lo = mid + 1; else hi = mid;
  }
  return lo;
}

__global__ __launch_bounds__(128) void pool_final_k(const int* __restrict__ batch,
                                                    const unsigned short* __restrict__ h3,
                                                    const float* __restrict__ Wl,
                                                    const float* __restrict__ bl,
                                                    float* __restrict__ out) {
  const int g = blockIdx.x;
  const int t = threadIdx.x;
  const int beg = lbound(batch, g);
  const int end = lbound(batch, g + 1);
  float s = 0.f;
  for (int n = beg; n < end; n++) s += bf2f(h3[(size_t)n * HH + t]);
  __shared__ float p[128];
  p[t] = s / (float)max(end - beg, 1);
  __syncthreads();
  float acc = bl[t];
#pragma unroll 8
  for (int h = 0; h < HH; h++) acc += p[h] * Wl[h * TT + t];
  out[(size_t)g * TT + t] = acc;
}

extern "C" void kernel_launch(void* const* d_in, const int* in_sizes, int n_in,
                              void* d_out, int out_size, void* d_ws, size_t ws_size,
                              hipStream_t stream) {
  const int*   x     = (const int*)d_in[0];
  const int*   ei    = (const int*)d_in[1];
  const int*   batch = (const int*)d_in[2];
  const float* emb   = (const float*)d_in[3];
  const float* W1    = (const float*)d_in[4];
  const float* b1    = (const float*)d_in[5];
  const float* W2    = (const float*)d_in[6];
  const float* b2    = (const float*)d_in[7];
  const float* W3    = (const float*)d_in[8];
  const float* b3    = (const float*)d_in[9];
  const float* Wl    = (const float*)d_in[10];
  const float* bl    = (const float*)d_in[11];
  float* out = (float*)d_out;

  // workspace layout (~57 MB)
  unsigned short* bufA = (unsigned short*)d_ws;        // N*H bf16 (h / agg, in-place)
  unsigned short* bufT = bufA + (size_t)NN * HH;       // N*H bf16 (Tm)
  unsigned short* Wt   = bufT + (size_t)NN * HH;       // 3*H*H bf16
  float* dinv   = (float*)(Wt + 3 * HH * HH);          // N
  int*   ptr    = (int*)(dinv + NN);                   // N+1
  int*   cnt    = ptr + NN + 1;                        // N
  int*   bsum   = cnt + NN;                            // 512
  int*   csr    = bsum + 512;                          // E

  hipMemsetAsync(cnt, 0, NN * sizeof(int), stream);

  const int NB = (NN + 255) / 256;

  deg_count_k<<<(EE + 255) / 256, 256, 0, stream>>>(ei, cnt);
  scan1_k<<<NB, 256, 0, stream>>>(cnt, ptr, bsum, dinv);
  scan2_k<<<1, 512, 0, stream>>>(bsum, NB);
  scan3_k<<<NB, 256, 0, stream>>>(ptr, bsum);
  fill_k<<<(EE + 255) / 256, 256, 0, stream>>>(ei, ptr, cnt, csr);

  atom_enc_k<<<NN / 16, 256, 0, stream>>>(x, emb, bufA);
  wtconv_k<<<HH, HH, 0, stream>>>(W1, Wt);
  wtconv_k<<<HH, HH, 0, stream>>>(W2, Wt + HH * HH);
  wtconv_k<<<HH, HH, 0, stream>>>(W3, Wt + 2 * HH * HH);

  const int gemm_grid = (NN + 127) / 128;
  const int agg_grid  = NN / 16;   // NN % 16 == 0

  gemm_mfma_k<<<gemm_grid, 256, 0, stream>>>(bufA, Wt, b1, dinv, bufT, bufA);
  agg_bf_k<true><<<agg_grid, 256, 0, stream>>>(ptr, csr, bufT, dinv, bufA, bufA);

  gemm_mfma_k<<<gemm_grid, 256, 0, stream>>>(bufA, Wt + HH * HH, b2, dinv, bufT, bufA);
  agg_bf_k<true><<<agg_grid, 256, 0, stream>>>(ptr, csr, bufT, dinv, bufA, bufA);

  gemm_mfma_k<<<gemm_grid, 256, 0, stream>>>(bufA, Wt + 2 * HH * HH, b3, dinv, bufT, bufA);
  agg_bf_k<false><<<agg_grid, 256, 0, stream>>>(ptr, csr, bufT, dinv, bufA, bufA);

  pool_final_k<<<GG, 128, 0, stream>>>(batch, bufA, Wl, bl, out);
}

// Round 5
// 380.019 us; speedup vs baseline: 4.9709x; 1.0263x over previous
//
#include <hip/hip_runtime.h>

#define NN 100000
#define EE 600000
#define HH 128
#define GG 4000
#define TT 128

typedef short short8 __attribute__((ext_vector_type(8)));
typedef unsigned short ushort8v __attribute__((ext_vector_type(8)));
typedef float floatx4 __attribute__((ext_vector_type(4)));

static __device__ __forceinline__ float bf2f(unsigned short u) {
  union { unsigned int i; float f; } v; v.i = ((unsigned int)u) << 16; return v.f;
}
static __device__ __forceinline__ unsigned short f2bf(float f) {
  union { float f; unsigned int i; } v; v.f = f;
  unsigned int r = (v.i + 0x7FFFu + ((v.i >> 16) & 1u)) >> 16;   // RNE
  return (unsigned short)r;
}

// ---------------- degree count (int) ----------------
__global__ __launch_bounds__(256) void deg_count_k(const int* __restrict__ ei,
                                                   int* __restrict__ cnt) {
  int e = blockIdx.x * 256 + threadIdx.x;
  if (e < EE) atomicAdd(&cnt[ei[EE + e]], 1);   // dst row
}

// ---------------- CSR build: 3-kernel exclusive scan (+dinv fused) ----------
__global__ __launch_bounds__(256) void scan1_k(const int* __restrict__ cnt,
                                               int* __restrict__ ptr,
                                               int* __restrict__ bsum,
                                               float* __restrict__ dinv) {
  const int i = blockIdx.x * 256 + threadIdx.x;
  int v = (i < NN) ? cnt[i] : 0;
  if (i < NN) dinv[i] = rsqrtf((float)v + 1.0f);   // +1 self-loop
  const int lane = threadIdx.x & 63, wid = threadIdx.x >> 6;
  int s = v;
#pragma unroll
  for (int off = 1; off < 64; off <<= 1) {
    int t = __shfl_up(s, off, 64);
    if (lane >= off) s += t;
  }
  __shared__ int wt[4];
  if (lane == 63) wt[wid] = s;
  __syncthreads();
  int wadd = 0;
  for (int w = 0; w < wid; w++) wadd += wt[w];
  int incl = s + wadd;
  if (i < NN) ptr[i] = incl - v;
  if (threadIdx.x == 255) bsum[blockIdx.x] = incl;
}

__global__ __launch_bounds__(512) void scan2_k(int* __restrict__ bsum, int nb) {
  const int t = threadIdx.x;
  int v = (t < nb) ? bsum[t] : 0;
  const int lane = t & 63, wid = t >> 6;
  int s = v;
#pragma unroll
  for (int off = 1; off < 64; off <<= 1) {
    int u = __shfl_up(s, off, 64);
    if (lane >= off) s += u;
  }
  __shared__ int wt[8];
  if (lane == 63) wt[wid] = s;
  __syncthreads();
  int wadd = 0;
  for (int w = 0; w < wid; w++) wadd += wt[w];
  int incl = s + wadd;
  if (t < nb) bsum[t] = incl - v;
}

__global__ __launch_bounds__(256) void scan3_k(int* __restrict__ ptr,
                                               const int* __restrict__ bsum) {
  const int i = blockIdx.x * 256 + threadIdx.x;
  if (i < NN) ptr[i] += bsum[blockIdx.x];
  if (i == 0) ptr[NN] = EE;
}

__global__ __launch_bounds__(256) void fill_k(const int* __restrict__ ei,
                                              const int* __restrict__ ptr,
                                              int* __restrict__ cnt,
                                              int* __restrict__ csr) {
  int e = blockIdx.x * 256 + threadIdx.x;
  if (e >= EE) return;
  int d = ei[EE + e];
  int ofs = atomicSub(&cnt[d], 1) - 1;
  csr[ptr[d] + ofs] = ei[e];                     // store src
}

// ---------------- atom encoder -> pre-scaled Hs0 = bf16(dinv * h0) ----------
__global__ __launch_bounds__(256) void atom_enc_k(const int* __restrict__ x,
                                                  const float* __restrict__ emb,
                                                  const float* __restrict__ dinv,
                                                  unsigned short* __restrict__ h0) {
  const int lane = threadIdx.x & 63;
  const int wid  = threadIdx.x >> 6;
  const int l16  = lane & 15;
  const int n = blockIdx.x * 16 + wid * 4 + (lane >> 4);   // grid*16 == NN
  const int off[9] = {0, 119, 124, 136, 148, 158, 164, 170, 172};
  int xv = (l16 < 9) ? x[n * 9 + l16] : 0;
  float s[8] = {0.f, 0.f, 0.f, 0.f, 0.f, 0.f, 0.f, 0.f};
#pragma unroll
  for (int f = 0; f < 9; f++) {
    int idx = __shfl(xv, (lane & 48) | f, 64) + off[f];
    const float* ep = emb + (size_t)idx * HH + l16 * 8;
    float4 e0 = *(const float4*)ep;
    float4 e1 = *(const float4*)(ep + 4);
    s[0] += e0.x; s[1] += e0.y; s[2] += e0.z; s[3] += e0.w;
    s[4] += e1.x; s[5] += e1.y; s[6] += e1.z; s[7] += e1.w;
  }
  const float dv = dinv[n];
  ushort8v o;
#pragma unroll
  for (int j = 0; j < 8; j++) o[j] = f2bf(dv * s[j]);
  *(ushort8v*)(h0 + (size_t)n * HH + l16 * 8) = o;
}

// ---------------- weight transpose+convert: Wt[n][k] = bf16(W[k][n]) --------
__global__ __launch_bounds__(128) void wtconv_k(const float* __restrict__ W,
                                                unsigned short* __restrict__ Wt) {
  const int n = blockIdx.x, k = threadIdx.x;
  Wt[n * HH + k] = f2bf(W[k * HH + n]);
}

// ---------------- CSR aggregation (before GEMM) ----------------
// Aggs[n] = bf16( dinv[n] * (Hs[n] + sum_{s in in(n)} Hs[s]) )
// (Hs pre-scaled by dinv, so this equals the symmetric-normalized aggregate
//  of H including the self-loop, all in pre-W space.)
__global__ __launch_bounds__(256) void agg_bf_k(const int* __restrict__ ptr,
                                                const int* __restrict__ csr,
                                                const unsigned short* __restrict__ Hs,
                                                const float* __restrict__ dinv,
                                                unsigned short* __restrict__ Aggs) {
  const int lane = threadIdx.x & 63;
  const int wid  = threadIdx.x >> 6;
  const int l16  = lane & 15;
  const int n = blockIdx.x * 16 + wid * 4 + (lane >> 4);   // grid*16 == NN
  const int beg = ptr[n], end = ptr[n + 1];
  float acc[8];
  {  // self row
    ushort8v v = *(const ushort8v*)(Hs + (size_t)n * HH + l16 * 8);
#pragma unroll
    for (int j = 0; j < 8; j++) acc[j] = bf2f(v[j]);
  }
  int i = beg;
  for (; i + 1 < end; i += 2) {
    int s0 = csr[i], s1 = csr[i + 1];
    ushort8v v0 = *(const ushort8v*)(Hs + (size_t)s0 * HH + l16 * 8);
    ushort8v v1 = *(const ushort8v*)(Hs + (size_t)s1 * HH + l16 * 8);
#pragma unroll
    for (int j = 0; j < 8; j++) acc[j] += bf2f(v0[j]) + bf2f(v1[j]);
  }
  if (i < end) {
    int s0 = csr[i];
    ushort8v v0 = *(const ushort8v*)(Hs + (size_t)s0 * HH + l16 * 8);
#pragma unroll
    for (int j = 0; j < 8; j++) acc[j] += bf2f(v0[j]);
  }
  const float dv = dinv[n];
  ushort8v o;
#pragma unroll
  for (int j = 0; j < 8; j++) o[j] = f2bf(dv * acc[j]);
  *(ushort8v*)(Aggs + (size_t)n * HH + l16 * 8) = o;
}

// ---------------- MFMA GEMM (after aggregation) ----------------
// C = Aggs @ W + b
// LAST==false: Hs_next = bf16(dinv * relu(C))   (pre-scaled for next agg)
// LAST==true : H3      = bf16(C)                (for pooling)
template <bool LAST>
__global__ __launch_bounds__(256) void gemm_mfma_k(const unsigned short* __restrict__ A,
                                                   const unsigned short* __restrict__ Wt,
                                                   const float* __restrict__ b,
                                                   const float* __restrict__ dinv,
                                                   unsigned short* __restrict__ Out) {
  const int w = threadIdx.x >> 6;
  const int l = threadIdx.x & 63;
  const int m16 = l & 15;              // row-in-tile (A) / col-in-tile (B, C)
  const int q8  = (l >> 4) * 8;        // k-offset of this lane's 8 elements
  const int bm  = blockIdx.x * 128 + w * 32;

  floatx4 acc[2][8];
#pragma unroll
  for (int i = 0; i < 2; i++)
#pragma unroll
    for (int j = 0; j < 8; j++) acc[i][j] = (floatx4){0.f, 0.f, 0.f, 0.f};

  for (int q = 0; q < 4; q++) {        // K = 128 in steps of 32
    const int k0 = q * 32;
    short8 a[2];
#pragma unroll
    for (int ti = 0; ti < 2; ti++) {
      int row = bm + ti * 16 + m16;
      a[ti] = (row < NN) ? *(const short8*)(A + (size_t)row * HH + k0 + q8)
                         : (short8){0, 0, 0, 0, 0, 0, 0, 0};
    }
#pragma unroll
    for (int tn = 0; tn < 8; tn++) {
      short8 bf = *(const short8*)(Wt + (size_t)(tn * 16 + m16) * HH + k0 + q8);
      acc[0][tn] = __builtin_amdgcn_mfma_f32_16x16x32_bf16(a[0], bf, acc[0][tn], 0, 0, 0);
      acc[1][tn] = __builtin_amdgcn_mfma_f32_16x16x32_bf16(a[1], bf, acc[1][tn], 0, 0, 0);
    }
  }

  float bias[8];
#pragma unroll
  for (int tn = 0; tn < 8; tn++) bias[tn] = b[tn * 16 + m16];

#pragma unroll
  for (int ti = 0; ti < 2; ti++) {
    const int rbase = bm + ti * 16 + (l >> 4) * 4;
#pragma unroll
    for (int r = 0; r < 4; r++) {
      const int row = rbase + r;
      if (row < NN) {
        const float dv = LAST ? 1.0f : dinv[row];
#pragma unroll
        for (int tn = 0; tn < 8; tn++) {
          const int col = tn * 16 + m16;
          float v = acc[ti][tn][r] + bias[tn];
          if (!LAST) v = dv * fmaxf(v, 0.f);
          Out[(size_t)row * HH + col] = f2bf(v);
        }
      }
    }
  }
}

// ---------------- fused pool + final linear ----------------
__device__ inline int lbound(const int* __restrict__ b, int val) {
  int lo = 0, hi = NN;
  while (lo < hi) {
    int mid = (lo + hi) >> 1;
    if (b[mid] < val) lo = mid + 1; else hi = mid;
  }
  return lo;
}

__global__ __launch_bounds__(128) void pool_final_k(const int* __restrict__ batch,
                                                    const unsigned short* __restrict__ h3,
                                                    const float* __restrict__ Wl,
                                                    const float* __restrict__ bl,
                                                    float* __restrict__ out) {
  const int g = blockIdx.x;
  const int t = threadIdx.x;
  const int beg = lbound(batch, g);
  const int end = lbound(batch, g + 1);
  float s = 0.f;
  for (int n = beg; n < end; n++) s += bf2f(h3[(size_t)n * HH + t]);
  __shared__ float p[128];
  p[t] = s / (float)max(end - beg, 1);
  __syncthreads();
  float acc = bl[t];
#pragma unroll 8
  for (int h = 0; h < HH; h++) acc += p[h] * Wl[h * TT + t];
  out[(size_t)g * TT + t] = acc;
}

extern "C" void kernel_launch(void* const* d_in, const int* in_sizes, int n_in,
                              void* d_out, int out_size, void* d_ws, size_t ws_size,
                              hipStream_t stream) {
  const int*   x     = (const int*)d_in[0];
  const int*   ei    = (const int*)d_in[1];
  const int*   batch = (const int*)d_in[2];
  const float* emb   = (const float*)d_in[3];
  const float* W1    = (const float*)d_in[4];
  const float* b1    = (const float*)d_in[5];
  const float* W2    = (const float*)d_in[6];
  const float* b2    = (const float*)d_in[7];
  const float* W3    = (const float*)d_in[8];
  const float* b3    = (const float*)d_in[9];
  const float* Wl    = (const float*)d_in[10];
  const float* bl    = (const float*)d_in[11];
  float* out = (float*)d_out;

  // workspace layout (~57 MB)
  unsigned short* bufA = (unsigned short*)d_ws;        // N*H bf16 (Hs / H3)
  unsigned short* bufB = bufA + (size_t)NN * HH;       // N*H bf16 (Aggs)
  unsigned short* Wt   = bufB + (size_t)NN * HH;       // 3*H*H bf16
  float* dinv   = (float*)(Wt + 3 * HH * HH);          // N
  int*   ptr    = (int*)(dinv + NN);                   // N+1
  int*   cnt    = ptr + NN + 1;                        // N
  int*   bsum   = cnt + NN;                            // 512
  int*   csr    = bsum + 512;                          // E

  hipMemsetAsync(cnt, 0, NN * sizeof(int), stream);

  const int NB = (NN + 255) / 256;

  deg_count_k<<<(EE + 255) / 256, 256, 0, stream>>>(ei, cnt);
  scan1_k<<<NB, 256, 0, stream>>>(cnt, ptr, bsum, dinv);
  scan2_k<<<1, 512, 0, stream>>>(bsum, NB);
  scan3_k<<<NB, 256, 0, stream>>>(ptr, bsum);
  fill_k<<<(EE + 255) / 256, 256, 0, stream>>>(ei, ptr, cnt, csr);

  atom_enc_k<<<NN / 16, 256, 0, stream>>>(x, emb, dinv, bufA);
  wtconv_k<<<HH, HH, 0, stream>>>(W1, Wt);
  wtconv_k<<<HH, HH, 0, stream>>>(W2, Wt + HH * HH);
  wtconv_k<<<HH, HH, 0, stream>>>(W3, Wt + 2 * HH * HH);

  const int gemm_grid = (NN + 127) / 128;
  const int agg_grid  = NN / 16;   // NN % 16 == 0

  agg_bf_k<<<agg_grid, 256, 0, stream>>>(ptr, csr, bufA, dinv, bufB);
  gemm_mfma_k<false><<<gemm_grid, 256, 0, stream>>>(bufB, Wt, b1, dinv, bufA);

  agg_bf_k<<<agg_grid, 256, 0, stream>>>(ptr, csr, bufA, dinv, bufB);
  gemm_mfma_k<false><<<gemm_grid, 256, 0, stream>>>(bufB, Wt + HH * HH, b2, dinv, bufA);

  agg_bf_k<<<agg_grid, 256, 0, stream>>>(ptr, csr, bufA, dinv, bufB);
  gemm_mfma_k<true><<<gemm_grid, 256, 0, stream>>>(bufB, Wt + 2 * HH * HH, b3, dinv, bufA);

  pool_final_k<<<GG, 128, 0, stream>>>(batch, bufA, Wl, bl, out);
}